// Round 1
// baseline (537.955 us; speedup 1.0000x reference)
//
#include <hip/hip_runtime.h>

typedef __bf16 bf16;
typedef __bf16 bf16x4 __attribute__((ext_vector_type(4)));
typedef __bf16 bf16x8 __attribute__((ext_vector_type(8)));
typedef float  f32x4  __attribute__((ext_vector_type(4)));

#define GLDS16(gsrc, ldst)                                                    \
  __builtin_amdgcn_global_load_lds(                                          \
      (const __attribute__((address_space(1))) void*)(gsrc),                 \
      (__attribute__((address_space(3))) void*)(ldst), 16, 0, 0)

// ---------------- f32 -> bf16 convert (vectorized x4) ----------------
__global__ __launch_bounds__(256) void cvt_kernel(const float* __restrict__ in,
                                                  bf16* __restrict__ out, int n4) {
  int i = blockIdx.x * 256 + threadIdx.x;
  if (i >= n4) return;
  f32x4 f = *(const f32x4*)(in + (size_t)i * 4);
  bf16x4 b;
#pragma unroll
  for (int j = 0; j < 4; ++j) b[j] = (bf16)f[j];
  *(bf16x4*)(out + (size_t)i * 4) = b;
}

// ---------------- RoPE (in place on bf16 buffer) ----------------
// t: (B*L) rows of `stride` elems; head hh at offset hh*64; thread owns pair (d, d+32).
__global__ __launch_bounds__(256) void rope_kernel(bf16* __restrict__ t,
                                                   const float* __restrict__ cosb,
                                                   const float* __restrict__ sinb,
                                                   int hlog, int stride, float scale) {
  int idx = blockIdx.x * 256 + threadIdx.x;
  int d   = idx & 31;
  int hh  = (idx >> 5) & ((1 << hlog) - 1);
  int row = idx >> (5 + hlog);
  int l   = row & 2047;
  float c1 = cosb[l * 64 + d],      s1 = sinb[l * 64 + d];
  float c2 = cosb[l * 64 + d + 32], s2 = sinb[l * 64 + d + 32];
  bf16* p = t + (size_t)row * stride + hh * 64 + d;
  float t1 = (float)p[0], t2 = (float)p[32];
  p[0]  = (bf16)((t1 * c1 - t2 * s1) * scale);  // rotated[d]    = -t[d+32]
  p[32] = (bf16)((t2 * c2 + t1 * s2) * scale);  // rotated[d+32] =  t[d]
}

// ---------------- C = A * B^T  (A: MxK, B: NxK row-major, bf16 MFMA) -------
// m97-class: 128x128 tile, BK=32, 4 waves (2x2), 4x4 16x16x32 MFMAs per wave.
template <typename OutT>
__global__ __launch_bounds__(256) void gemm_bt(const bf16* __restrict__ A,
                                               const bf16* __restrict__ Bm,
                                               OutT* __restrict__ C,
                                               int M, int N, int K) {
  __shared__ bf16 a_lds[128 * 32];
  __shared__ bf16 b_lds[128 * 32];
  const int tid = threadIdx.x;
  const int w = tid >> 6, lane = tid & 63;
  const int lr = lane & 15, lg = lane >> 4;
  const int wr = w >> 1, wc = w & 1;
  const int m0 = blockIdx.y * 128, n0 = blockIdx.x * 128;

  f32x4 acc[4][4];
#pragma unroll
  for (int i = 0; i < 4; ++i)
#pragma unroll
    for (int j = 0; j < 4; ++j) acc[i][j] = f32x4{0.f, 0.f, 0.f, 0.f};

  for (int kt = 0; kt < K; kt += 32) {
#pragma unroll
    for (int i = 0; i < 2; ++i) {
      int c = tid + 256 * i;      // chunk: row = c>>2, k-chunk = c&3 (8 bf16 = 16B)
      int row = c >> 2, kc = c & 3;
      GLDS16(A  + (size_t)(m0 + row) * K + kt + kc * 8, &a_lds[(w * 64 + 256 * i) * 8]);
      GLDS16(Bm + (size_t)(n0 + row) * K + kt + kc * 8, &b_lds[(w * 64 + 256 * i) * 8]);
    }
    __syncthreads();   // drains vmcnt for global_load_lds
    bf16x8 af[4], bfr[4];
#pragma unroll
    for (int t = 0; t < 4; ++t) {
      af[t]  = *(const bf16x8*)&a_lds[(wr * 64 + t * 16 + lr) * 32 + lg * 8];
      bfr[t] = *(const bf16x8*)&b_lds[(wc * 64 + t * 16 + lr) * 32 + lg * 8];
    }
#pragma unroll
    for (int mt = 0; mt < 4; ++mt)
#pragma unroll
      for (int nt = 0; nt < 4; ++nt)
        acc[mt][nt] = __builtin_amdgcn_mfma_f32_16x16x32_bf16(af[mt], bfr[nt],
                                                              acc[mt][nt], 0, 0, 0);
    __syncthreads();
  }

#pragma unroll
  for (int mt = 0; mt < 4; ++mt)
#pragma unroll
    for (int nt = 0; nt < 4; ++nt)
#pragma unroll
      for (int r = 0; r < 4; ++r) {
        int mm = m0 + wr * 64 + mt * 16 + 4 * lg + r;   // C/D: row = 4*(l>>4)+reg
        int nn = n0 + wc * 64 + nt * 16 + lr;           //      col = l&15
        C[(size_t)mm * N + nn] = (OutT)acc[mt][nt][r];
      }
}

// ---------------- causal GQA flash attention ----------------
// grid (L/64, B*H), 256 thr = 4 waves; wave w owns q rows [q0+16w, q0+16w+16).
// q/k/v live in the fused QKV buffer: row stride 3072; o row stride 2048.
__global__ __launch_bounds__(256) void attn_kernel(const bf16* __restrict__ q,
                                                   const bf16* __restrict__ k,
                                                   const bf16* __restrict__ v,
                                                   bf16* __restrict__ o) {
  constexpr int L = 2048;
  constexpr int QS = 3072;   // qkv row stride (elements)
  constexpr int OS = 2048;   // o row stride
  const int q0 = blockIdx.x * 64;
  const int bh = blockIdx.y;
  const int b = bh >> 5, h = bh & 31, g = h >> 2;
  const int tid = threadIdx.x;
  const int w = tid >> 6, lane = tid & 63;
  const int lr = lane & 15, lg = lane >> 4;
  const int qw = q0 + w * 16;

  __shared__ bf16 k_lds[64 * 64];        // [kv][d]
  __shared__ bf16 vt_lds[64 * 64];       // [d][kv] (transposed for B-frag reads)
  __shared__ bf16 p_lds[4][16 * 64];     // per-wave P tile [q][kv]

  bf16x8 qf0, qf1;                       // A-frag: row=lr (q), k=8*lg+j (+32)
  {
    const bf16* qp = q + (size_t)(b * L + qw + lr) * QS + h * 64 + lg * 8;
    qf0 = *(const bf16x8*)qp;
    qf1 = *(const bf16x8*)(qp + 32);
  }

  f32x4 acc[4];                          // O: d-tile t; col=d=lr, row=q=4*lg+r
#pragma unroll
  for (int t = 0; t < 4; ++t) acc[t] = f32x4{0.f, 0.f, 0.f, 0.f};
  float m_run[4], l_run[4];
#pragma unroll
  for (int r = 0; r < 4; ++r) { m_run[r] = -1e30f; l_run[r] = 0.f; }

  for (int kv0 = 0; kv0 <= q0; kv0 += 64) {
    // stage K tile 64x64 via global_load_lds (linear LDS, 16B/lane)
#pragma unroll
    for (int i = 0; i < 2; ++i) {
      int c = tid + 256 * i;  // row = c>>3, 16B chunk = c&7
      GLDS16(k + (size_t)(b * L + kv0 + (c >> 3)) * QS + g * 64 + (c & 7) * 8,
             &k_lds[(w * 64 + 256 * i) * 8]);
    }
    // stage V transposed (reg-staged; global_load_lds can't scatter)
#pragma unroll
    for (int i = 0; i < 2; ++i) {
      int c = tid + 256 * i;
      int row = c >> 3, c8 = c & 7;
      bf16x8 vv = *(const bf16x8*)(v + (size_t)(b * L + kv0 + row) * QS + g * 64 + c8 * 8);
#pragma unroll
      for (int j = 0; j < 8; ++j) vt_lds[(c8 * 8 + j) * 64 + row] = vv[j];
    }
    __syncthreads();

    // S = Q K^T : 4 kv-tiles of 16, 2 MFMAs each (d halves). s[t][r]:
    //   q = qw + 4*lg + r, kv = kv0 + 16t + lr
    f32x4 s[4];
#pragma unroll
    for (int t = 0; t < 4; ++t) {
      const bf16* kp = &k_lds[(t * 16 + lr) * 64 + lg * 8];  // B: col=kv=lr, k=d
      bf16x8 kf0 = *(const bf16x8*)kp;
      bf16x8 kf1 = *(const bf16x8*)(kp + 32);
      f32x4 z = f32x4{0.f, 0.f, 0.f, 0.f};
      z = __builtin_amdgcn_mfma_f32_16x16x32_bf16(qf0, kf0, z, 0, 0, 0);
      z = __builtin_amdgcn_mfma_f32_16x16x32_bf16(qf1, kf1, z, 0, 0, 0);
      s[t] = z;
    }

    // causal mask (scale already folded into q)
#pragma unroll
    for (int t = 0; t < 4; ++t)
#pragma unroll
      for (int r = 0; r < 4; ++r)
        if (kv0 + t * 16 + lr > qw + 4 * lg + r) s[t][r] = -1e30f;

    // online softmax; row stats shared by the 16-lane group (same lg)
    float al[4];
#pragma unroll
    for (int r = 0; r < 4; ++r) {
      float m2 = fmaxf(fmaxf(s[0][r], s[1][r]), fmaxf(s[2][r], s[3][r]));
#pragma unroll
      for (int sh = 1; sh < 16; sh <<= 1) m2 = fmaxf(m2, __shfl_xor(m2, sh));
      float mn = fmaxf(m_run[r], m2);
      al[r] = __expf(m_run[r] - mn);
      m_run[r] = mn;
      float p0 = 0.f;
#pragma unroll
      for (int t = 0; t < 4; ++t) {
        float pe = __expf(s[t][r] - mn);
        s[t][r] = pe;
        p0 += pe;
      }
#pragma unroll
      for (int sh = 1; sh < 16; sh <<= 1) p0 += __shfl_xor(p0, sh);
      l_run[r] = l_run[r] * al[r] + p0;
    }

    // P (C-frag layout) -> LDS -> A-frag layout
#pragma unroll
    for (int t = 0; t < 4; ++t)
#pragma unroll
      for (int r = 0; r < 4; ++r)
        p_lds[w][(4 * lg + r) * 64 + t * 16 + lr] = (bf16)s[t][r];

    asm volatile("s_waitcnt lgkmcnt(0)" ::: "memory");  // wave-private RAW fence

    // rescale O
#pragma unroll
    for (int t = 0; t < 4; ++t)
#pragma unroll
      for (int r = 0; r < 4; ++r) acc[t][r] *= al[r];

    // O += P V : A-frag from p_lds (row=lr=q, k=kv), B-frag from vt (col=d, k=kv)
    const bf16* pp = &p_lds[w][lr * 64 + lg * 8];
    bf16x8 pf0 = *(const bf16x8*)pp;
    bf16x8 pf1 = *(const bf16x8*)(pp + 32);
#pragma unroll
    for (int t = 0; t < 4; ++t) {
      const bf16* vp = &vt_lds[(t * 16 + lr) * 64 + lg * 8];
      bf16x8 vf0 = *(const bf16x8*)vp;
      bf16x8 vf1 = *(const bf16x8*)(vp + 32);
      acc[t] = __builtin_amdgcn_mfma_f32_16x16x32_bf16(pf0, vf0, acc[t], 0, 0, 0);
      acc[t] = __builtin_amdgcn_mfma_f32_16x16x32_bf16(pf1, vf1, acc[t], 0, 0, 0);
    }
    __syncthreads();
  }

#pragma unroll
  for (int t = 0; t < 4; ++t)
#pragma unroll
    for (int r = 0; r < 4; ++r) {
      float oo = acc[t][r] / l_run[r];
      o[(size_t)(b * L + qw + 4 * lg + r) * OS + h * 64 + t * 16 + lr] = (bf16)oo;
    }
}

extern "C" void kernel_launch(void* const* d_in, const int* in_sizes, int n_in,
                              void* d_out, int out_size, void* d_ws, size_t ws_size,
                              hipStream_t stream) {
  (void)in_sizes; (void)n_in; (void)out_size; (void)ws_size;
  const float* x    = (const float*)d_in[0];
  const float* cosb = (const float*)d_in[1];
  const float* sinb = (const float*)d_in[2];
  const float* Wq   = (const float*)d_in[3];
  const float* Wk   = (const float*)d_in[4];
  const float* Wv   = (const float*)d_in[5];
  const float* Wo   = (const float*)d_in[6];

  constexpr int B = 2, L = 2048, D = 2048, H = 32, G = 8;
  constexpr int M = B * L;           // 4096
  constexpr int DKV = G * 64;        // 512
  constexpr int NQKV = D + 2 * DKV;  // 3072

  // workspace: xb | wqkv | wob | qkv   (ob aliases xb — xb is dead after the QKV GEMM)
  char* p = (char*)d_ws;
  bf16* xb   = (bf16*)p; p += (size_t)M * D * 2;
  bf16* wqkv = (bf16*)p; p += (size_t)NQKV * D * 2;
  bf16* wob  = (bf16*)p; p += (size_t)D * D * 2;
  bf16* qkv  = (bf16*)p; p += (size_t)M * NQKV * 2;
  bf16* ob   = xb;

  auto cvt = [&](const float* src, bf16* dst, size_t n) {
    int n4 = (int)(n / 4);
    cvt_kernel<<<(n4 + 255) / 256, 256, 0, stream>>>(src, dst, n4);
  };
  cvt(x,  xb,                           (size_t)M * D);
  cvt(Wq, wqkv,                         (size_t)D * D);
  cvt(Wk, wqkv + (size_t)D * D,         (size_t)DKV * D);
  cvt(Wv, wqkv + (size_t)(D + DKV) * D, (size_t)DKV * D);
  cvt(Wo, wob,                          (size_t)D * D);

  // fused QKV projection: (4096 x 2048) * (3072 x 2048)^T
  gemm_bt<bf16><<<dim3(NQKV / 128, M / 128), 256, 0, stream>>>(xb, wqkv, qkv, M, NQKV, D);

  // RoPE in place; fold softmax scale 1/sqrt(64) into q
  rope_kernel<<<(M * H * 32) / 256, 256, 0, stream>>>(qkv,     cosb, sinb, 5, NQKV, 0.125f);
  rope_kernel<<<(M * G * 32) / 256, 256, 0, stream>>>(qkv + D, cosb, sinb, 3, NQKV, 1.0f);

  attn_kernel<<<dim3(L / 64, B * H), 256, 0, stream>>>(qkv, qkv + D, qkv + D + DKV, ob);

  // output projection: (4096 x 2048) * (2048 x 2048)^T -> f32 d_out
  gemm_bt<float><<<dim3(D / 128, M / 128), 256, 0, stream>>>(ob, wob, (float*)d_out, M, D, D);
}

// Round 2
// 404.900 us; speedup vs baseline: 1.3286x; 1.3286x over previous
//
#include <hip/hip_runtime.h>

typedef __bf16 bf16;
typedef __bf16 bf16x4 __attribute__((ext_vector_type(4)));
typedef __bf16 bf16x8 __attribute__((ext_vector_type(8)));
typedef float  f32x4  __attribute__((ext_vector_type(4)));

#define GLDS16(gsrc, ldst)                                                    \
  __builtin_amdgcn_global_load_lds(                                          \
      (const __attribute__((address_space(1))) void*)(gsrc),                 \
      (__attribute__((address_space(3))) void*)(ldst), 16, 0, 0)

#define MFMA16(a, b, c) __builtin_amdgcn_mfma_f32_16x16x32_bf16((a), (b), (c), 0, 0, 0)

// ---------------- f32 -> bf16 convert (vectorized x4) ----------------
__global__ __launch_bounds__(256) void cvt_kernel(const float* __restrict__ in,
                                                  bf16* __restrict__ out, int n4) {
  int i = blockIdx.x * 256 + threadIdx.x;
  if (i >= n4) return;
  f32x4 f = *(const f32x4*)(in + (size_t)i * 4);
  bf16x4 b;
#pragma unroll
  for (int j = 0; j < 4; ++j) b[j] = (bf16)f[j];
  *(bf16x4*)(out + (size_t)i * 4) = b;
}

// ---------------- RoPE (in place on bf16 buffer) ----------------
__global__ __launch_bounds__(256) void rope_kernel(bf16* __restrict__ t,
                                                   const float* __restrict__ cosb,
                                                   const float* __restrict__ sinb,
                                                   int hlog, int stride, float scale) {
  int idx = blockIdx.x * 256 + threadIdx.x;
  int d   = idx & 31;
  int hh  = (idx >> 5) & ((1 << hlog) - 1);
  int row = idx >> (5 + hlog);
  int l   = row & 2047;
  float c1 = cosb[l * 64 + d],      s1 = sinb[l * 64 + d];
  float c2 = cosb[l * 64 + d + 32], s2 = sinb[l * 64 + d + 32];
  bf16* p = t + (size_t)row * stride + hh * 64 + d;
  float t1 = (float)p[0], t2 = (float)p[32];
  p[0]  = (bf16)((t1 * c1 - t2 * s1) * scale);
  p[32] = (bf16)((t2 * c2 + t1 * s2) * scale);
}

// ---------------- C = A * B^T  (A: MxK, B: NxK row-major, bf16 MFMA) -------
template <typename OutT>
__global__ __launch_bounds__(256) void gemm_bt(const bf16* __restrict__ A,
                                               const bf16* __restrict__ Bm,
                                               OutT* __restrict__ C,
                                               int M, int N, int K) {
  __shared__ bf16 a_lds[128 * 32];
  __shared__ bf16 b_lds[128 * 32];
  const int tid = threadIdx.x;
  const int w = tid >> 6, lane = tid & 63;
  const int lr = lane & 15, lg = lane >> 4;
  const int wr = w >> 1, wc = w & 1;
  const int m0 = blockIdx.y * 128, n0 = blockIdx.x * 128;

  f32x4 acc[4][4];
#pragma unroll
  for (int i = 0; i < 4; ++i)
#pragma unroll
    for (int j = 0; j < 4; ++j) acc[i][j] = f32x4{0.f, 0.f, 0.f, 0.f};

  for (int kt = 0; kt < K; kt += 32) {
#pragma unroll
    for (int i = 0; i < 2; ++i) {
      int c = tid + 256 * i;
      int row = c >> 2, kc = c & 3;
      GLDS16(A  + (size_t)(m0 + row) * K + kt + kc * 8, &a_lds[(w * 64 + 256 * i) * 8]);
      GLDS16(Bm + (size_t)(n0 + row) * K + kt + kc * 8, &b_lds[(w * 64 + 256 * i) * 8]);
    }
    __syncthreads();
    bf16x8 af[4], bfr[4];
#pragma unroll
    for (int t = 0; t < 4; ++t) {
      af[t]  = *(const bf16x8*)&a_lds[(wr * 64 + t * 16 + lr) * 32 + lg * 8];
      bfr[t] = *(const bf16x8*)&b_lds[(wc * 64 + t * 16 + lr) * 32 + lg * 8];
    }
#pragma unroll
    for (int mt = 0; mt < 4; ++mt)
#pragma unroll
      for (int nt = 0; nt < 4; ++nt)
        acc[mt][nt] = MFMA16(af[mt], bfr[nt], acc[mt][nt]);
    __syncthreads();
  }

#pragma unroll
  for (int mt = 0; mt < 4; ++mt)
#pragma unroll
    for (int nt = 0; nt < 4; ++nt)
#pragma unroll
      for (int r = 0; r < 4; ++r) {
        int mm = m0 + wr * 64 + mt * 16 + 4 * lg + r;
        int nn = n0 + wc * 64 + nt * 16 + lr;
        C[(size_t)mm * N + nn] = (OutT)acc[mt][nt][r];
      }
}

// ---------------- causal GQA flash attention ----------------
// grid (L/128, B*H), 256 thr = 4 waves; wave w owns 32 q rows [q0+32w, q0+32w+32).
// Double-buffered K (swizzled global_load_lds) and V^T (shfl-pair-packed b32
// writes, word-swizzled). P via padded-72 LDS. One barrier per KV tile.
__global__ __launch_bounds__(256) void attn_kernel(const bf16* __restrict__ q,
                                                   const bf16* __restrict__ k,
                                                   const bf16* __restrict__ v,
                                                   bf16* __restrict__ o) {
  constexpr int L = 2048;
  constexpr int QS = 3072;   // qkv row stride (elements)
  constexpr int OS = 2048;   // o row stride
  const int q0 = blockIdx.x * 128;
  const int bh = blockIdx.y;
  const int b = bh >> 5, h = bh & 31, g = h >> 2;
  const int tid = threadIdx.x;
  const int w = tid >> 6, lane = tid & 63;
  const int lr = lane & 15, lg = lane >> 4;
  const int qw = q0 + w * 32;

  __shared__ bf16     k_lds[2][64 * 64];   // [kv][d], 16B-chunk XOR-swizzled
  __shared__ unsigned vt_w[2][64 * 32];    // V^T [d][kv-pair words], word-swizzled
  __shared__ bf16     p_lds[4][32 * 72];   // per-wave P [q][kv], pad 64->72

  // Q fragments (A-frag: row=lr, k=8*lg+j), scale folded in by rope_kernel
  bf16x8 qf[2][2];
#pragma unroll
  for (int qt = 0; qt < 2; ++qt) {
    const bf16* qp = q + (size_t)(b * L + qw + qt * 16 + lr) * QS + h * 64 + lg * 8;
    qf[qt][0] = *(const bf16x8*)qp;
    qf[qt][1] = *(const bf16x8*)(qp + 32);
  }

  f32x4 acc[2][4];
  float m_run[2][4], l_run[2][4];
#pragma unroll
  for (int qt = 0; qt < 2; ++qt)
#pragma unroll
    for (int i = 0; i < 4; ++i) {
      acc[qt][i] = f32x4{0.f, 0.f, 0.f, 0.f};
      m_run[qt][i] = -1e30f;
      l_run[qt][i] = 0.f;
    }

  uint4 uv[2];  // in-flight V registers (issue-early / write-late)

  auto stageK = [&](int kv0, int buf) {
#pragma unroll
    for (int i = 0; i < 2; ++i) {
      int c = tid + 256 * i;
      int kvr = c >> 3, c8 = c & 7;
      // pre-swizzled SOURCE chunk so linear LDS holds swizzled layout (rule #21)
      GLDS16(k + (size_t)(b * L + kv0 + kvr) * QS + g * 64 + ((c8 ^ (kvr & 7)) * 8),
             &k_lds[buf][(w * 64 + 256 * i) * 8]);
    }
  };
  auto loadV = [&](int kv0) {
#pragma unroll
    for (int i = 0; i < 2; ++i) {
      int c = tid + 256 * i;
      uv[i] = *(const uint4*)(v + (size_t)(b * L + kv0 + (c >> 3)) * QS + g * 64 + (c & 7) * 8);
    }
  };
  auto writeV = [&](int buf) {
#pragma unroll
    for (int i = 0; i < 2; ++i) {
      int c = tid + 256 * i;
      int kvr = c >> 3, c8 = c & 7;
      unsigned o0 = uv[i].x, o1 = uv[i].y, o2 = uv[i].z, o3 = uv[i].w;
      unsigned p0 = (unsigned)__shfl_xor((int)o0, 8);
      unsigned p1 = (unsigned)__shfl_xor((int)o1, 8);
      unsigned p2 = (unsigned)__shfl_xor((int)o2, 8);
      unsigned p3 = (unsigned)__shfl_xor((int)o3, 8);
      int pr = kvr & 1, kvw = kvr >> 1;
#pragma unroll
      for (int jj = 0; jj < 4; ++jj) {
        // own/partner u32 holding element jd = 4*pr + jj  (index 2*pr + (jj>>1))
        unsigned ow = (jj >> 1) ? (pr ? o3 : o1) : (pr ? o2 : o0);
        unsigned pw = (jj >> 1) ? (pr ? p3 : p1) : (pr ? p2 : p0);
        unsigned oe = (jj & 1) ? (ow >> 16) : (ow & 0xFFFFu);
        unsigned pe = (jj & 1) ? (pw >> 16) : (pw & 0xFFFFu);
        unsigned lo = pr ? pe : oe;   // even-kv element
        unsigned hi = pr ? oe : pe;   // odd-kv element
        int d = 8 * c8 + 4 * pr + jj;
        vt_w[buf][d * 32 + (kvw ^ (c8 << 2))] = lo | (hi << 16);
      }
    }
  };

  const int nt = q0 / 64 + 2;   // kv tiles: kv0 = 0 .. q0+64
  stageK(0, 0);
  loadV(0);
  writeV(0);
  __syncthreads();

  for (int it = 0; it < nt; ++it) {
    const int cur = it & 1;
    const int kv0 = it * 64;
    const bool notlast = (it + 1 < nt);
    if (notlast) {           // issue next-tile loads before compute (T14)
      stageK(kv0 + 64, cur ^ 1);
      loadV(kv0 + 64);
    }

    if (kv0 <= qw + 31) {    // wave-uniform: skip fully-masked tail tiles
      // ---- S = Q K^T ----
      f32x4 s[2][4];
#pragma unroll
      for (int t = 0; t < 4; ++t) {
        int krow = t * 16 + lr;
        int pc = lg ^ (krow & 7);
        bf16x8 kf0 = *(const bf16x8*)&k_lds[cur][krow * 64 + pc * 8];
        bf16x8 kf1 = *(const bf16x8*)&k_lds[cur][krow * 64 + (pc ^ 4) * 8];
#pragma unroll
        for (int qt = 0; qt < 2; ++qt) {
          f32x4 z = f32x4{0.f, 0.f, 0.f, 0.f};
          z = MFMA16(qf[qt][0], kf0, z);
          z = MFMA16(qf[qt][1], kf1, z);
          s[qt][t] = z;
        }
      }

      // ---- causal mask ----
#pragma unroll
      for (int qt = 0; qt < 2; ++qt) {
        if (kv0 + 63 > qw + qt * 16) {
#pragma unroll
          for (int t = 0; t < 4; ++t)
#pragma unroll
            for (int r = 0; r < 4; ++r)
              if (kv0 + t * 16 + lr > qw + qt * 16 + 4 * lg + r) s[qt][t][r] = -1e30f;
        }
      }

      // ---- online softmax (16-lane-group shfl reduce) + P write ----
#pragma unroll
      for (int qt = 0; qt < 2; ++qt)
#pragma unroll
        for (int r = 0; r < 4; ++r) {
          float m2 = fmaxf(fmaxf(s[qt][0][r], s[qt][1][r]),
                           fmaxf(s[qt][2][r], s[qt][3][r]));
#pragma unroll
          for (int sh = 1; sh < 16; sh <<= 1) m2 = fmaxf(m2, __shfl_xor(m2, sh));
          float mn = fmaxf(m_run[qt][r], m2);
          float alr = __expf(m_run[qt][r] - mn);
          m_run[qt][r] = mn;
          float ps = 0.f;
#pragma unroll
          for (int t = 0; t < 4; ++t) {
            float pe = __expf(s[qt][t][r] - mn);
            s[qt][t][r] = pe;
            ps += pe;
          }
#pragma unroll
          for (int sh = 1; sh < 16; sh <<= 1) ps += __shfl_xor(ps, sh);
          l_run[qt][r] = l_run[qt][r] * alr + ps;
#pragma unroll
          for (int t = 0; t < 4; ++t) acc[qt][t][r] *= alr;
#pragma unroll
          for (int t = 0; t < 4; ++t)
            p_lds[w][(qt * 16 + 4 * lg + r) * 72 + t * 16 + lr] = (bf16)s[qt][t][r];
        }

      asm volatile("s_waitcnt lgkmcnt(0)" ::: "memory");  // wave-private P RAW fence

      // ---- O += P V ----
      bf16x8 pf[2][2];
#pragma unroll
      for (int qt = 0; qt < 2; ++qt) {
        const bf16* pp = &p_lds[w][(qt * 16 + lr) * 72];
        pf[qt][0] = *(const bf16x8*)(pp + lg * 8);
        pf[qt][1] = *(const bf16x8*)(pp + 32 + lg * 8);
      }
#pragma unroll
      for (int t = 0; t < 4; ++t) {
        int drow = t * 16 + lr;
        int x = (drow >> 3) & 7;
        bf16x8 vf0 = *(const bf16x8*)&vt_w[cur][drow * 32 + ((lg ^ x) << 2)];
        bf16x8 vf1 = *(const bf16x8*)&vt_w[cur][drow * 32 + ((4 + lg) ^ x) * 4];
#pragma unroll
        for (int qt = 0; qt < 2; ++qt) {
          acc[qt][t] = MFMA16(pf[qt][0], vf0, acc[qt][t]);
          acc[qt][t] = MFMA16(pf[qt][1], vf1, acc[qt][t]);
        }
      }
    }

    if (notlast) writeV(cur ^ 1);   // write-late: HBM latency hidden under compute
    __syncthreads();                // publishes K (vmcnt drain) + V for next iter
  }

#pragma unroll
  for (int qt = 0; qt < 2; ++qt)
#pragma unroll
    for (int r = 0; r < 4; ++r) {
      float rl = 1.0f / l_run[qt][r];
#pragma unroll
      for (int t = 0; t < 4; ++t)
        o[(size_t)(b * L + qw + qt * 16 + 4 * lg + r) * OS + h * 64 + t * 16 + lr] =
            (bf16)(acc[qt][t][r] * rl);
    }
}

extern "C" void kernel_launch(void* const* d_in, const int* in_sizes, int n_in,
                              void* d_out, int out_size, void* d_ws, size_t ws_size,
                              hipStream_t stream) {
  (void)in_sizes; (void)n_in; (void)out_size; (void)ws_size;
  const float* x    = (const float*)d_in[0];
  const float* cosb = (const float*)d_in[1];
  const float* sinb = (const float*)d_in[2];
  const float* Wq   = (const float*)d_in[3];
  const float* Wk   = (const float*)d_in[4];
  const float* Wv   = (const float*)d_in[5];
  const float* Wo   = (const float*)d_in[6];

  constexpr int B = 2, L = 2048, D = 2048, H = 32, G = 8;
  constexpr int M = B * L;           // 4096
  constexpr int DKV = G * 64;        // 512
  constexpr int NQKV = D + 2 * DKV;  // 3072

  char* p = (char*)d_ws;
  bf16* xb   = (bf16*)p; p += (size_t)M * D * 2;
  bf16* wqkv = (bf16*)p; p += (size_t)NQKV * D * 2;
  bf16* wob  = (bf16*)p; p += (size_t)D * D * 2;
  bf16* qkv  = (bf16*)p; p += (size_t)M * NQKV * 2;
  bf16* ob   = xb;  // xb dead after QKV GEMM

  auto cvt = [&](const float* src, bf16* dst, size_t n) {
    int n4 = (int)(n / 4);
    cvt_kernel<<<(n4 + 255) / 256, 256, 0, stream>>>(src, dst, n4);
  };
  cvt(x,  xb,                           (size_t)M * D);
  cvt(Wq, wqkv,                         (size_t)D * D);
  cvt(Wk, wqkv + (size_t)D * D,         (size_t)DKV * D);
  cvt(Wv, wqkv + (size_t)(D + DKV) * D, (size_t)DKV * D);
  cvt(Wo, wob,                          (size_t)D * D);

  gemm_bt<bf16><<<dim3(NQKV / 128, M / 128), 256, 0, stream>>>(xb, wqkv, qkv, M, NQKV, D);

  rope_kernel<<<(M * H * 32) / 256, 256, 0, stream>>>(qkv,     cosb, sinb, 5, NQKV, 0.125f);
  rope_kernel<<<(M * G * 32) / 256, 256, 0, stream>>>(qkv + D, cosb, sinb, 3, NQKV, 1.0f);

  attn_kernel<<<dim3(L / 128, B * H), 256, 0, stream>>>(qkv, qkv + D, qkv + D + DKV, ob);

  gemm_bt<float><<<dim3(D / 128, M / 128), 256, 0, stream>>>(ob, wob, (float*)d_out, M, D, D);
}

// Round 3
// 304.538 us; speedup vs baseline: 1.7665x; 1.3296x over previous
//
#include <hip/hip_runtime.h>

typedef __bf16 bf16;
typedef __bf16 bf16x4 __attribute__((ext_vector_type(4)));
typedef __bf16 bf16x8 __attribute__((ext_vector_type(8)));
typedef float  f32x4  __attribute__((ext_vector_type(4)));
typedef float  f32x16 __attribute__((ext_vector_type(16)));

#define GLDS16(gsrc, ldst)                                                    \
  __builtin_amdgcn_global_load_lds(                                          \
      (const __attribute__((address_space(1))) void*)(gsrc),                 \
      (__attribute__((address_space(3))) void*)(ldst), 16, 0, 0)

#define MFMA16(a, b, c) __builtin_amdgcn_mfma_f32_16x16x32_bf16((a), (b), (c), 0, 0, 0)
#define MFMA32(a, b, c) __builtin_amdgcn_mfma_f32_32x32x16_bf16((a), (b), (c), 0, 0, 0)
// exchange a's hi-32-lane half with b's lo-32-lane half (gfx950)
#define PLSWAP(a, b) asm volatile("v_permlane32_swap_b32 %0, %1" : "+v"(a), "+v"(b))

__device__ inline unsigned pk2(float a, float b) {
  union { bf16 h[2]; unsigned u; } t;
  t.h[0] = (bf16)a; t.h[1] = (bf16)b;
  return t.u;
}

// ---------------- f32 -> bf16 convert (vectorized x4) ----------------
__global__ __launch_bounds__(256) void cvt_kernel(const float* __restrict__ in,
                                                  bf16* __restrict__ out, int n4) {
  int i = blockIdx.x * 256 + threadIdx.x;
  if (i >= n4) return;
  f32x4 f = *(const f32x4*)(in + (size_t)i * 4);
  bf16x4 b;
#pragma unroll
  for (int j = 0; j < 4; ++j) b[j] = (bf16)f[j];
  *(bf16x4*)(out + (size_t)i * 4) = b;
}

// ---------------- RoPE (in place on bf16 buffer) ----------------
__global__ __launch_bounds__(256) void rope_kernel(bf16* __restrict__ t,
                                                   const float* __restrict__ cosb,
                                                   const float* __restrict__ sinb,
                                                   int hlog, int stride, float scale) {
  int idx = blockIdx.x * 256 + threadIdx.x;
  int d   = idx & 31;
  int hh  = (idx >> 5) & ((1 << hlog) - 1);
  int row = idx >> (5 + hlog);
  int l   = row & 2047;
  float c1 = cosb[l * 64 + d],      s1 = sinb[l * 64 + d];
  float c2 = cosb[l * 64 + d + 32], s2 = sinb[l * 64 + d + 32];
  bf16* p = t + (size_t)row * stride + hh * 64 + d;
  float t1 = (float)p[0], t2 = (float)p[32];
  p[0]  = (bf16)((t1 * c1 - t2 * s1) * scale);
  p[32] = (bf16)((t2 * c2 + t1 * s2) * scale);
}

// ---------------- C = A * B^T  (A: MxK, B: NxK row-major, bf16 MFMA) -------
template <typename OutT>
__global__ __launch_bounds__(256) void gemm_bt(const bf16* __restrict__ A,
                                               const bf16* __restrict__ Bm,
                                               OutT* __restrict__ C,
                                               int M, int N, int K) {
  __shared__ bf16 a_lds[128 * 32];
  __shared__ bf16 b_lds[128 * 32];
  const int tid = threadIdx.x;
  const int w = tid >> 6, lane = tid & 63;
  const int lr = lane & 15, lg = lane >> 4;
  const int wr = w >> 1, wc = w & 1;
  const int m0 = blockIdx.y * 128, n0 = blockIdx.x * 128;

  f32x4 acc[4][4];
#pragma unroll
  for (int i = 0; i < 4; ++i)
#pragma unroll
    for (int j = 0; j < 4; ++j) acc[i][j] = f32x4{0.f, 0.f, 0.f, 0.f};

  for (int kt = 0; kt < K; kt += 32) {
#pragma unroll
    for (int i = 0; i < 2; ++i) {
      int c = tid + 256 * i;
      int row = c >> 2, kc = c & 3;
      GLDS16(A  + (size_t)(m0 + row) * K + kt + kc * 8, &a_lds[(w * 64 + 256 * i) * 8]);
      GLDS16(Bm + (size_t)(n0 + row) * K + kt + kc * 8, &b_lds[(w * 64 + 256 * i) * 8]);
    }
    __syncthreads();
    bf16x8 af[4], bfr[4];
#pragma unroll
    for (int t = 0; t < 4; ++t) {
      af[t]  = *(const bf16x8*)&a_lds[(wr * 64 + t * 16 + lr) * 32 + lg * 8];
      bfr[t] = *(const bf16x8*)&b_lds[(wc * 64 + t * 16 + lr) * 32 + lg * 8];
    }
#pragma unroll
    for (int mt = 0; mt < 4; ++mt)
#pragma unroll
      for (int nt = 0; nt < 4; ++nt)
        acc[mt][nt] = MFMA16(af[mt], bfr[nt], acc[mt][nt]);
    __syncthreads();
  }

#pragma unroll
  for (int mt = 0; mt < 4; ++mt)
#pragma unroll
    for (int nt = 0; nt < 4; ++nt)
#pragma unroll
      for (int r = 0; r < 4; ++r) {
        int mm = m0 + wr * 64 + mt * 16 + 4 * lg + r;
        int nn = n0 + wc * 64 + nt * 16 + lr;
        C[(size_t)mm * N + nn] = (OutT)acc[mt][nt][r];
      }
}

// ---------------- causal GQA flash attention (swapped QK^T, 32x32) ----------
// grid (16, B*H), 256 thr = 4 waves; wave w owns 32 q rows. Heavy-tiles-first.
// P fully in-register: mfma(K,Q) puts P column q=lane&31 in-lane; softmax is
// 31 in-reg ops + one shfl_xor(32). P->A-frag via pack+v_permlane32_swap (T12).
// Defer-max THR=8 (T13). K: chunk-XOR swizzled global_load_lds. V^T: padded
// stride-36-word LDS (write conflict-free, read at b128 floor).
__global__ __launch_bounds__(256, 4) void attn_kernel(const bf16* __restrict__ q,
                                                      const bf16* __restrict__ k,
                                                      const bf16* __restrict__ v,
                                                      bf16* __restrict__ o) {
  constexpr int L = 2048;
  constexpr int QS = 3072;   // qkv row stride (elements)
  constexpr int OS = 2048;   // o row stride
  const int q0 = ((int)gridDim.x - 1 - (int)blockIdx.x) * 128;  // heavy first (LPT)
  const int bh = blockIdx.y;
  const int b = bh >> 5, h = bh & 31, g = h >> 2;
  const int tid = threadIdx.x;
  const int w = tid >> 6, lane = tid & 63;
  const int lc = lane & 31;        // q column (QK) / d column (PV)
  const int H  = lane >> 5;
  const int off4 = 4 * H;
  const int qw = q0 + w * 32;
  const int qg = qw + lc;          // this lane's q row (global)

  __shared__ bf16     k_lds[2][64 * 64];   // [kv][d], 16B-chunk XOR-swizzled
  __shared__ unsigned vt_w[2][64 * 36];    // V^T [d][kv-pair], padded stride 36

  // Q B-frag: col=q=lc, k(d) = 16s + 8H + j
  bf16x8 qf[4];
  {
    const bf16* qrow = q + (size_t)(b * L + qg) * QS + h * 64 + 8 * H;
#pragma unroll
    for (int s = 0; s < 4; ++s) qf[s] = *(const bf16x8*)(qrow + 16 * s);
  }

  f32x16 acc0, acc1;
#pragma unroll
  for (int r = 0; r < 16; ++r) { acc0[r] = 0.f; acc1[r] = 0.f; }
  float m_run = -1e30f, l_run = 0.f;

  uint4 uv[2];  // in-flight V (issue-early / write-late)

  auto stageK = [&](int kv0, int buf) {
#pragma unroll
    for (int i = 0; i < 2; ++i) {
      int c = tid + 256 * i;
      int kvr = c >> 3, c8 = c & 7;
      GLDS16(k + (size_t)(b * L + kv0 + kvr) * QS + g * 64 + ((c8 ^ (kvr & 7)) * 8),
             &k_lds[buf][(w * 64 + 256 * i) * 8]);
    }
  };
  auto loadV = [&](int kv0) {
#pragma unroll
    for (int i = 0; i < 2; ++i) {
      int c = tid + 256 * i;
      uv[i] = *(const uint4*)(v + (size_t)(b * L + kv0 + (c >> 3)) * QS + g * 64 + (c & 7) * 8);
    }
  };
  auto writeV = [&](int buf) {
#pragma unroll
    for (int i = 0; i < 2; ++i) {
      int c = tid + 256 * i;
      int kvr = c >> 3, c8 = c & 7;
      unsigned o0 = uv[i].x, o1 = uv[i].y, o2 = uv[i].z, o3 = uv[i].w;
      unsigned p0 = (unsigned)__shfl_xor((int)o0, 8);
      unsigned p1 = (unsigned)__shfl_xor((int)o1, 8);
      unsigned p2 = (unsigned)__shfl_xor((int)o2, 8);
      unsigned p3 = (unsigned)__shfl_xor((int)o3, 8);
      int pr = kvr & 1, kvw = kvr >> 1;
#pragma unroll
      for (int jj = 0; jj < 4; ++jj) {
        unsigned ow = (jj >> 1) ? (pr ? o3 : o1) : (pr ? o2 : o0);
        unsigned pw = (jj >> 1) ? (pr ? p3 : p1) : (pr ? p2 : p0);
        unsigned oe = (jj & 1) ? (ow >> 16) : (ow & 0xFFFFu);
        unsigned pe = (jj & 1) ? (pw >> 16) : (pw & 0xFFFFu);
        unsigned lo = pr ? pe : oe;   // even kv
        unsigned hi = pr ? oe : pe;   // odd kv
        int d = 8 * c8 + 4 * pr + jj;
        vt_w[buf][d * 36 + kvw] = lo | (hi << 16);
      }
    }
  };

  const int nt = q0 / 64 + 2;
  stageK(0, 0);
  loadV(0);
  writeV(0);
  __syncthreads();

  for (int it = 0; it < nt; ++it) {
    const int cur = it & 1;
    const int kv0 = it * 64;
    const bool notlast = (it + 1 < nt);
    if (notlast) {
      stageK(kv0 + 64, cur ^ 1);
      loadV(kv0 + 64);
    }

    if (kv0 <= qw + 31) {   // wave-uniform skip of fully-masked tiles
      // ---- S = K Q (A=K rows=kv, B=Q cols=q) ----
      f32x16 p0, p1;
#pragma unroll
      for (int r = 0; r < 16; ++r) { p0[r] = 0.f; p1[r] = 0.f; }
#pragma unroll
      for (int s = 0; s < 4; ++s) {
        int ch = ((2 * s + H) ^ (lc & 7)) * 8;
        bf16x8 kf0 = *(const bf16x8*)&k_lds[cur][lc * 64 + ch];
        bf16x8 kf1 = *(const bf16x8*)&k_lds[cur][(32 + lc) * 64 + ch];
        p0 = MFMA32(kf0, qf[s], p0);
        p1 = MFMA32(kf1, qf[s], p1);
      }

      // ---- causal mask: D row=kv=(r&3)+8(r>>2)+4H, col=q=lc ----
      if (kv0 + 63 > qw) {
#pragma unroll
        for (int r = 0; r < 16; ++r) {
          int kvl = kv0 + (r & 3) + 8 * (r >> 2) + off4;
          if (kvl > qg)      p0[r] = -1e30f;
          if (kvl + 32 > qg) p1[r] = -1e30f;
        }
      }

      // ---- online softmax, in-register (T12) + defer-max (T13) ----
      float mt = -1e30f;
#pragma unroll
      for (int r = 0; r < 16; ++r) mt = fmaxf(mt, fmaxf(p0[r], p1[r]));
      mt = fmaxf(mt, __shfl_xor(mt, 32));
      const int defer = __all(mt <= m_run + 8.f);
      float alpha = 1.f;
      if (!defer) {
        float mn = fmaxf(m_run, mt);
        alpha = __expf(m_run - mn);
        m_run = mn;
      }
      float ls = 0.f;
#pragma unroll
      for (int r = 0; r < 16; ++r) {
        p0[r] = __expf(p0[r] - m_run);
        p1[r] = __expf(p1[r] - m_run);
        ls += p0[r] + p1[r];
      }
      ls += __shfl_xor(ls, 32);
      l_run = l_run * alpha + ls;
      if (!defer) {
#pragma unroll
        for (int r = 0; r < 16; ++r) {
          float aq = __shfl(alpha, ((r & 3) + 8 * (r >> 2)) + off4);
          acc0[r] *= aq;
          acc1[r] *= aq;
        }
      }

      // ---- P -> bf16 A-frags: pack pairs, permlane32_swap redistributes ----
      unsigned A[16];
#pragma unroll
      for (int i = 0; i < 8; ++i) {
        A[i]     = pk2(p0[2 * i], p0[2 * i + 1]);
        A[8 + i] = pk2(p1[2 * i], p1[2 * i + 1]);
      }
#pragma unroll
      for (int base = 0; base < 16; base += 4) {
        PLSWAP(A[base],     A[base + 2]);
        PLSWAP(A[base + 1], A[base + 3]);
      }

      // ---- O += P V  (A=P rows=q, B=V cols=d) ----
#pragma unroll
      for (int sp = 0; sp < 4; ++sp) {
        union { unsigned u[4]; bf16x8 v8; } pa;
#pragma unroll
        for (int j = 0; j < 4; ++j) pa.u[j] = A[4 * sp + j];
        const int kwoff = 8 * sp + 4 * H;
        bf16x8 vf0 = *(const bf16x8*)&vt_w[cur][lc * 36 + kwoff];
        bf16x8 vf1 = *(const bf16x8*)&vt_w[cur][(32 + lc) * 36 + kwoff];
        acc0 = MFMA32(pa.v8, vf0, acc0);
        acc1 = MFMA32(pa.v8, vf1, acc1);
      }
    }

    if (notlast) writeV(cur ^ 1);
    __syncthreads();
  }

  // ---- epilogue: divide by l (per-q, via shfl) and store ----
#pragma unroll
  for (int r = 0; r < 16; ++r) {
    int qrow = (r & 3) + 8 * (r >> 2) + off4;
    float lq = __shfl(l_run, qrow);
    float inv = 1.f / lq;
    size_t orow = (size_t)(b * L + qw + qrow) * OS + h * 64;
    o[orow + lc]      = (bf16)(acc0[r] * inv);
    o[orow + 32 + lc] = (bf16)(acc1[r] * inv);
  }
}

extern "C" void kernel_launch(void* const* d_in, const int* in_sizes, int n_in,
                              void* d_out, int out_size, void* d_ws, size_t ws_size,
                              hipStream_t stream) {
  (void)in_sizes; (void)n_in; (void)out_size; (void)ws_size;
  const float* x    = (const float*)d_in[0];
  const float* cosb = (const float*)d_in[1];
  const float* sinb = (const float*)d_in[2];
  const float* Wq   = (const float*)d_in[3];
  const float* Wk   = (const float*)d_in[4];
  const float* Wv   = (const float*)d_in[5];
  const float* Wo   = (const float*)d_in[6];

  constexpr int B = 2, L = 2048, D = 2048, H = 32, G = 8;
  constexpr int M = B * L;           // 4096
  constexpr int DKV = G * 64;        // 512
  constexpr int NQKV = D + 2 * DKV;  // 3072

  char* p = (char*)d_ws;
  bf16* xb   = (bf16*)p; p += (size_t)M * D * 2;
  bf16* wqkv = (bf16*)p; p += (size_t)NQKV * D * 2;
  bf16* wob  = (bf16*)p; p += (size_t)D * D * 2;
  bf16* qkv  = (bf16*)p; p += (size_t)M * NQKV * 2;
  bf16* ob   = xb;  // xb dead after QKV GEMM

  auto cvt = [&](const float* src, bf16* dst, size_t n) {
    int n4 = (int)(n / 4);
    cvt_kernel<<<(n4 + 255) / 256, 256, 0, stream>>>(src, dst, n4);
  };
  cvt(x,  xb,                           (size_t)M * D);
  cvt(Wq, wqkv,                         (size_t)D * D);
  cvt(Wk, wqkv + (size_t)D * D,         (size_t)DKV * D);
  cvt(Wv, wqkv + (size_t)(D + DKV) * D, (size_t)DKV * D);
  cvt(Wo, wob,                          (size_t)D * D);

  gemm_bt<bf16><<<dim3(NQKV / 128, M / 128), 256, 0, stream>>>(xb, wqkv, qkv, M, NQKV, D);

  rope_kernel<<<(M * H * 32) / 256, 256, 0, stream>>>(qkv,     cosb, sinb, 5, NQKV, 0.125f);
  rope_kernel<<<(M * G * 32) / 256, 256, 0, stream>>>(qkv + D, cosb, sinb, 3, NQKV, 1.0f);

  attn_kernel<<<dim3(L / 128, B * H), 256, 0, stream>>>(qkv, qkv + D, qkv + D + DKV, ob);

  gemm_bt<float><<<dim3(D / 128, M / 128), 256, 0, stream>>>(ob, wob, (float*)d_out, M, D, D);
}